// Round 1
// baseline (494.837 us; speedup 1.0000x reference)
//
#include <hip/hip_runtime.h>
#include <hip/hip_bf16.h>
#include <cstdint>
#include <cstddef>

// BertMoE: B=4,S=2048,H=768,F=3072,E=8,K=2. tokens T=8192.
#define T_TOK 8192
#define HDIM  768
#define FDIM  3072
#define NEXP  8

typedef __attribute__((ext_vector_type(8))) __bf16 bf16x8;
typedef __attribute__((ext_vector_type(4))) float  f32x4;

static __device__ __forceinline__ f32x4 mfma16(bf16x8 a, bf16x8 b, f32x4 c) {
  return __builtin_amdgcn_mfma_f32_16x16x32_bf16(a, b, c, 0, 0, 0);
}

static __device__ __forceinline__ void gload16(const void* g, void* l) {
  __builtin_amdgcn_global_load_lds(
      (const __attribute__((address_space(1))) void*)g,
      (__attribute__((address_space(3))) void*)l, 16, 0, 0);
}

static __device__ __forceinline__ unsigned short f2b(float f) {
  return __builtin_bit_cast(unsigned short, (__bf16)f);
}

// ---------------- workspace layout (bytes) ----------------
// xb   : T*H bf16            = 12,582,912
// wib  : E*F*H bf16          = 37,748,736
// wob  : E*H*F bf16          = 37,748,736
// hbuf : 2T*F bf16           = 100,663,296
// meta : counts(32) @+0, base(32) @+64, cursor(32) @+128   (256 total)
// tok_e, tok_w, pair_tok, pair_w : 65,536 each
static constexpr size_t OFF_XB   = 0;
static constexpr size_t OFF_WIB  = OFF_XB  + (size_t)T_TOK * HDIM * 2;
static constexpr size_t OFF_WOB  = OFF_WIB + (size_t)NEXP * FDIM * HDIM * 2;
static constexpr size_t OFF_HBUF = OFF_WOB + (size_t)NEXP * HDIM * FDIM * 2;
static constexpr size_t OFF_META = OFF_HBUF + (size_t)2 * T_TOK * FDIM * 2;
static constexpr size_t OFF_TOKE = OFF_META + 256;
static constexpr size_t OFF_TOKW = OFF_TOKE + 65536;
static constexpr size_t OFF_PTOK = OFF_TOKW + 65536;
static constexpr size_t OFF_PW   = OFF_PTOK + 65536;

// ---------------- fp32 -> bf16 convert ----------------
__global__ __launch_bounds__(256) void cvt_kernel(const float* __restrict__ s,
                                                  unsigned short* __restrict__ d, int n4) {
  int i = blockIdx.x * 256 + threadIdx.x;
  int stride = gridDim.x * 256;
  for (; i < n4; i += stride) {
    float4 v = ((const float4*)s)[i];
    ushort4 o;
    o.x = f2b(v.x); o.y = f2b(v.y); o.z = f2b(v.z); o.w = f2b(v.w);
    ((ushort4*)d)[i] = o;
  }
}

// ---------------- router: logits, top2, softmax ----------------
__global__ __launch_bounds__(256) void router_kernel(const float* __restrict__ x,
                                                     const float* __restrict__ Wr,
                                                     int* __restrict__ tok_e,
                                                     float* __restrict__ tok_w) {
  __shared__ float wr[NEXP * HDIM];
  int tid = threadIdx.x;
  for (int i = tid; i < NEXP * HDIM; i += 256) wr[i] = Wr[i];
  __syncthreads();
  int lane = tid & 63;
  int wv = tid >> 6;
  int t = blockIdx.x * 4 + wv;
  const float* xr = x + (size_t)t * HDIM;
  float p[NEXP];
#pragma unroll
  for (int e = 0; e < NEXP; ++e) p[e] = 0.f;
  for (int j = 0; j < HDIM / 64; ++j) {
    float xv = xr[j * 64 + lane];
#pragma unroll
    for (int e = 0; e < NEXP; ++e) p[e] += xv * wr[e * HDIM + j * 64 + lane];
  }
#pragma unroll
  for (int e = 0; e < NEXP; ++e) {
    float v = p[e];
    for (int off = 32; off; off >>= 1) v += __shfl_xor(v, off);
    p[e] = v;
  }
  if (lane == 0) {
    float v0 = -1e30f, v1 = -1e30f; int i0 = 0, i1 = 0;
#pragma unroll
    for (int e = 0; e < NEXP; ++e) {
      float v = p[e];
      if (v > v0) { v1 = v0; i1 = i0; v0 = v; i0 = e; }
      else if (v > v1) { v1 = v; i1 = e; }
    }
    float ew = expf(v1 - v0);
    float w0 = 1.0f / (1.0f + ew);
    float w1 = ew * w0;
    tok_e[t * 2 + 0] = i0; tok_w[t * 2 + 0] = w0;
    tok_e[t * 2 + 1] = i1; tok_w[t * 2 + 1] = w1;
  }
}

// ---------------- count / scan / scatter ----------------
__global__ __launch_bounds__(256) void count_kernel(const int* __restrict__ tok_e,
                                                    int* __restrict__ counts) {
  __shared__ int h[NEXP];
  int tid = threadIdx.x;
  if (tid < NEXP) h[tid] = 0;
  __syncthreads();
  int i = blockIdx.x * 256 + tid;
  atomicAdd(&h[tok_e[i]], 1);
  __syncthreads();
  if (tid < NEXP && h[tid] > 0) atomicAdd(&counts[tid], h[tid]);
}

__global__ void scan_kernel(const int* __restrict__ counts, int* __restrict__ base) {
  if (threadIdx.x == 0 && blockIdx.x == 0) {
    int s = 0;
    for (int e = 0; e < NEXP; ++e) { base[e] = s; s += counts[e]; }
  }
}

__global__ __launch_bounds__(256) void scatter_kernel(const int* __restrict__ tok_e,
                                                      const float* __restrict__ tok_w,
                                                      const int* __restrict__ base,
                                                      int* __restrict__ cursor,
                                                      int* __restrict__ pair_tok,
                                                      float* __restrict__ pair_w) {
  __shared__ int h[NEXP], bstart[NEXP];
  int tid = threadIdx.x;
  if (tid < NEXP) h[tid] = 0;
  __syncthreads();
  int i = blockIdx.x * 256 + tid;
  int e = tok_e[i];
  int r = atomicAdd(&h[e], 1);
  __syncthreads();
  if (tid < NEXP) bstart[tid] = (h[tid] > 0) ? atomicAdd(&cursor[tid], h[tid]) : 0;
  __syncthreads();
  int pos = base[e] + bstart[e] + r;
  pair_tok[pos] = i >> 1;
  pair_w[pos] = tok_w[i];
}

// ---------------- pass A: H = gelu(X * Wi^T + bi), bf16 out ----------------
__global__ __launch_bounds__(256) void gemmA_kernel(
    const unsigned short* __restrict__ xb, const unsigned short* __restrict__ wib,
    const float* __restrict__ bi, const int* __restrict__ counts,
    const int* __restrict__ base, const int* __restrict__ pair_tok,
    unsigned short* __restrict__ hbuf) {
  const int e = blockIdx.z;
  const int ne = counts[e];
  const int mt = blockIdx.y;
  if (mt * 128 >= ne) return;
  const int nt = blockIdx.x;
  const int pb = base[e];

  __shared__ __bf16 As[128 * 64];
  __shared__ __bf16 Bs[128 * 64];

  const int tid = threadIdx.x;
  const int lane = tid & 63;
  const int wv = tid >> 6;
  const int wm = wv >> 1, wn = wv & 1;
  const int lrow = lane & 15;
  const int lk = (lane >> 4) * 8;

  const unsigned short* aSrc[4];
  const unsigned short* bSrc[4];
#pragma unroll
  for (int it = 0; it < 4; ++it) {
    int flat = it * 4096 + tid * 16;   // byte offset within 16KB tile
    int row = flat >> 7;               // 128B per row (64 bf16)
    int ke = (flat & 127) >> 1;        // element offset within row
    int ra = mt * 128 + row; if (ra > ne - 1) ra = ne - 1;
    int tok = pair_tok[pb + ra];
    aSrc[it] = xb + (size_t)tok * HDIM + ke;
    bSrc[it] = wib + (size_t)e * (FDIM * HDIM) + (size_t)(nt * 128 + row) * HDIM + ke;
  }

  f32x4 acc[4][4];
#pragma unroll
  for (int mi = 0; mi < 4; ++mi)
#pragma unroll
    for (int ni = 0; ni < 4; ++ni) acc[mi][ni] = (f32x4){0.f, 0.f, 0.f, 0.f};

  for (int kt = 0; kt < HDIM; kt += 64) {
#pragma unroll
    for (int it = 0; it < 4; ++it) {
      gload16(aSrc[it] + kt, &As[it * 2048 + tid * 8]);
      gload16(bSrc[it] + kt, &Bs[it * 2048 + tid * 8]);
    }
    __syncthreads();
#pragma unroll
    for (int kk = 0; kk < 64; kk += 32) {
      bf16x8 af[4], bfr[4];
#pragma unroll
      for (int mi = 0; mi < 4; ++mi)
        af[mi] = *(const bf16x8*)&As[(wm * 64 + mi * 16 + lrow) * 64 + kk + lk];
#pragma unroll
      for (int ni = 0; ni < 4; ++ni)
        bfr[ni] = *(const bf16x8*)&Bs[(wn * 64 + ni * 16 + lrow) * 64 + kk + lk];
#pragma unroll
      for (int mi = 0; mi < 4; ++mi)
#pragma unroll
        for (int ni = 0; ni < 4; ++ni)
          acc[mi][ni] = mfma16(af[mi], bfr[ni], acc[mi][ni]);
    }
    __syncthreads();
  }

  const float* bie = bi + (size_t)e * FDIM;
#pragma unroll
  for (int mi = 0; mi < 4; ++mi) {
#pragma unroll
    for (int r = 0; r < 4; ++r) {
      int row = mt * 128 + wm * 64 + mi * 16 + (lane >> 4) * 4 + r;
      if (row < ne) {
        size_t rb = (size_t)(pb + row) * FDIM;
#pragma unroll
        for (int ni = 0; ni < 4; ++ni) {
          int col = nt * 128 + wn * 64 + ni * 16 + lrow;
          float v = acc[mi][ni][r] + bie[col];
          v = 0.5f * v * (1.0f + erff(v * 0.70710678118654752f));
          hbuf[rb + col] = f2b(v);
        }
      }
    }
  }
}

// ---------------- pass B: out += w * (H * Wo^T + bo) ----------------
__global__ __launch_bounds__(256) void gemmB_kernel(
    const unsigned short* __restrict__ hbuf, const unsigned short* __restrict__ wob,
    const float* __restrict__ bo, const int* __restrict__ counts,
    const int* __restrict__ base, const int* __restrict__ pair_tok,
    const float* __restrict__ pair_w, float* __restrict__ out) {
  const int e = blockIdx.z;
  const int ne = counts[e];
  const int mt = blockIdx.y;
  if (mt * 128 >= ne) return;
  const int nt = blockIdx.x;   // 0..5
  const int pb = base[e];

  __shared__ __bf16 As[128 * 64];
  __shared__ __bf16 Bs[128 * 64];

  const int tid = threadIdx.x;
  const int lane = tid & 63;
  const int wv = tid >> 6;
  const int wm = wv >> 1, wn = wv & 1;
  const int lrow = lane & 15;
  const int lk = (lane >> 4) * 8;

  const unsigned short* aSrc[4];
  const unsigned short* bSrc[4];
#pragma unroll
  for (int it = 0; it < 4; ++it) {
    int flat = it * 4096 + tid * 16;
    int row = flat >> 7;
    int ke = (flat & 127) >> 1;
    int ra = mt * 128 + row; if (ra > ne - 1) ra = ne - 1;
    aSrc[it] = hbuf + (size_t)(pb + ra) * FDIM + ke;
    bSrc[it] = wob + (size_t)e * (HDIM * FDIM) + (size_t)(nt * 128 + row) * FDIM + ke;
  }

  f32x4 acc[4][4];
#pragma unroll
  for (int mi = 0; mi < 4; ++mi)
#pragma unroll
    for (int ni = 0; ni < 4; ++ni) acc[mi][ni] = (f32x4){0.f, 0.f, 0.f, 0.f};

  for (int kt = 0; kt < FDIM; kt += 64) {
#pragma unroll
    for (int it = 0; it < 4; ++it) {
      gload16(aSrc[it] + kt, &As[it * 2048 + tid * 8]);
      gload16(bSrc[it] + kt, &Bs[it * 2048 + tid * 8]);
    }
    __syncthreads();
#pragma unroll
    for (int kk = 0; kk < 64; kk += 32) {
      bf16x8 af[4], bfr[4];
#pragma unroll
      for (int mi = 0; mi < 4; ++mi)
        af[mi] = *(const bf16x8*)&As[(wm * 64 + mi * 16 + lrow) * 64 + kk + lk];
#pragma unroll
      for (int ni = 0; ni < 4; ++ni)
        bfr[ni] = *(const bf16x8*)&Bs[(wn * 64 + ni * 16 + lrow) * 64 + kk + lk];
#pragma unroll
      for (int mi = 0; mi < 4; ++mi)
#pragma unroll
        for (int ni = 0; ni < 4; ++ni)
          acc[mi][ni] = mfma16(af[mi], bfr[ni], acc[mi][ni]);
    }
    __syncthreads();
  }

  const float* boe = bo + (size_t)e * HDIM;
#pragma unroll
  for (int mi = 0; mi < 4; ++mi) {
#pragma unroll
    for (int r = 0; r < 4; ++r) {
      int row = mt * 128 + wm * 64 + mi * 16 + (lane >> 4) * 4 + r;
      if (row < ne) {
        int p = pb + row;
        int tok = pair_tok[p];
        float w = pair_w[p];
        float* orow = out + (size_t)tok * HDIM;
#pragma unroll
        for (int ni = 0; ni < 4; ++ni) {
          int col = nt * 128 + wn * 64 + ni * 16 + lrow;
          float v = (acc[mi][ni][r] + boe[col]) * w;
          atomicAdd(&orow[col], v);
        }
      }
    }
  }
}

extern "C" void kernel_launch(void* const* d_in, const int* in_sizes, int n_in,
                              void* d_out, int out_size, void* d_ws, size_t ws_size,
                              hipStream_t stream) {
  const float* x  = (const float*)d_in[0];
  const float* Wr = (const float*)d_in[1];
  const float* Wi = (const float*)d_in[2];
  const float* bi = (const float*)d_in[3];
  const float* Wo = (const float*)d_in[4];
  const float* bo = (const float*)d_in[5];
  float* out = (float*)d_out;
  char* ws = (char*)d_ws;

  unsigned short* xb   = (unsigned short*)(ws + OFF_XB);
  unsigned short* wib  = (unsigned short*)(ws + OFF_WIB);
  unsigned short* wob  = (unsigned short*)(ws + OFF_WOB);
  unsigned short* hbuf = (unsigned short*)(ws + OFF_HBUF);
  int*   counts   = (int*)(ws + OFF_META);
  int*   basep    = (int*)(ws + OFF_META + 64);
  int*   cursor   = (int*)(ws + OFF_META + 128);
  int*   tok_e    = (int*)(ws + OFF_TOKE);
  float* tok_w    = (float*)(ws + OFF_TOKW);
  int*   pair_tok = (int*)(ws + OFF_PTOK);
  float* pair_w   = (float*)(ws + OFF_PW);

  hipMemsetAsync(ws + OFF_META, 0, 256, stream);
  hipMemsetAsync(d_out, 0, (size_t)T_TOK * HDIM * sizeof(float), stream);

  cvt_kernel<<<1024, 256, 0, stream>>>(x, xb, T_TOK * HDIM / 4);
  cvt_kernel<<<2048, 256, 0, stream>>>(Wi, wib, NEXP * FDIM * HDIM / 4);
  cvt_kernel<<<2048, 256, 0, stream>>>(Wo, wob, NEXP * HDIM * FDIM / 4);

  router_kernel<<<T_TOK / 4, 256, 0, stream>>>(x, Wr, tok_e, tok_w);
  count_kernel<<<64, 256, 0, stream>>>(tok_e, counts);
  scan_kernel<<<1, 64, 0, stream>>>(counts, basep);
  scatter_kernel<<<64, 256, 0, stream>>>(tok_e, tok_w, basep, cursor, pair_tok, pair_w);

  gemmA_kernel<<<dim3(FDIM / 128, T_TOK / 128, NEXP), 256, 0, stream>>>(
      xb, wib, bi, counts, basep, pair_tok, hbuf);
  gemmB_kernel<<<dim3(HDIM / 128, T_TOK / 128, NEXP), 256, 0, stream>>>(
      hbuf, wob, bo, counts, basep, pair_tok, pair_w, out);
}

// Round 2
// 332.603 us; speedup vs baseline: 1.4878x; 1.4878x over previous
//
#include <hip/hip_runtime.h>
#include <hip/hip_bf16.h>
#include <cstdint>
#include <cstddef>

// BertMoE: B=4,S=2048,H=768,F=3072,E=8,K=2. tokens T=8192, pairs=16384.
#define T_TOK 8192
#define HDIM  768
#define FDIM  3072
#define NEXP  8

typedef __attribute__((ext_vector_type(8))) __bf16 bf16x8;
typedef __attribute__((ext_vector_type(4))) float  f32x4;

static __device__ __forceinline__ f32x4 mfma16(bf16x8 a, bf16x8 b, f32x4 c) {
  return __builtin_amdgcn_mfma_f32_16x16x32_bf16(a, b, c, 0, 0, 0);
}

static __device__ __forceinline__ unsigned short f2b(float f) {
  return __builtin_bit_cast(unsigned short, (__bf16)f);
}

// ---------------- workspace layout (bytes) ----------------
static constexpr size_t OFF_XB   = 0;                                     // T*H bf16   = 12.58 MB
static constexpr size_t OFF_WIB  = OFF_XB  + (size_t)T_TOK * HDIM * 2;    // E*F*H bf16 = 37.75 MB
static constexpr size_t OFF_WOB  = OFF_WIB + (size_t)NEXP * FDIM * HDIM * 2; // E*H*F bf16
static constexpr size_t OFF_HBUF = OFF_WOB + (size_t)NEXP * HDIM * FDIM * 2; // 2T*F bf16 = 100.7 MB
static constexpr size_t OFF_META = OFF_HBUF + (size_t)2 * T_TOK * FDIM * 2;
static constexpr size_t OFF_TOKE = OFF_META + 256;
static constexpr size_t OFF_TOKW = OFF_TOKE + 65536;
static constexpr size_t OFF_PTOK = OFF_TOKW + 65536;
static constexpr size_t OFF_PW   = OFF_PTOK + 65536;
// stage [16384][768] f32 = 50.33 MB: ALIASES xb+wib (dead once gemmA is done)
static constexpr size_t OFF_STAGE = 0;

// ---------------- fp32 -> bf16 convert ----------------
__global__ __launch_bounds__(256) void cvt_kernel(const float* __restrict__ s,
                                                  unsigned short* __restrict__ d, int n4) {
  int i = blockIdx.x * 256 + threadIdx.x;
  int stride = gridDim.x * 256;
  for (; i < n4; i += stride) {
    float4 v = ((const float4*)s)[i];
    ushort4 o;
    o.x = f2b(v.x); o.y = f2b(v.y); o.z = f2b(v.z); o.w = f2b(v.w);
    ((ushort4*)d)[i] = o;
  }
}

// ---------------- router: logits, top2, softmax ----------------
__global__ __launch_bounds__(256) void router_kernel(const float* __restrict__ x,
                                                     const float* __restrict__ Wr,
                                                     int* __restrict__ tok_e,
                                                     float* __restrict__ tok_w) {
  __shared__ float wr[NEXP * HDIM];
  int tid = threadIdx.x;
  for (int i = tid; i < NEXP * HDIM; i += 256) wr[i] = Wr[i];
  __syncthreads();
  int lane = tid & 63;
  int wv = tid >> 6;
  int t = blockIdx.x * 4 + wv;
  const float* xr = x + (size_t)t * HDIM;
  float p[NEXP];
#pragma unroll
  for (int e = 0; e < NEXP; ++e) p[e] = 0.f;
  for (int j = 0; j < HDIM / 64; ++j) {
    float xv = xr[j * 64 + lane];
#pragma unroll
    for (int e = 0; e < NEXP; ++e) p[e] += xv * wr[e * HDIM + j * 64 + lane];
  }
#pragma unroll
  for (int e = 0; e < NEXP; ++e) {
    float v = p[e];
    for (int off = 32; off; off >>= 1) v += __shfl_xor(v, off);
    p[e] = v;
  }
  if (lane == 0) {
    float v0 = -1e30f, v1 = -1e30f; int i0 = 0, i1 = 0;
#pragma unroll
    for (int e = 0; e < NEXP; ++e) {
      float v = p[e];
      if (v > v0) { v1 = v0; i1 = i0; v0 = v; i0 = e; }
      else if (v > v1) { v1 = v; i1 = e; }
    }
    float ew = expf(v1 - v0);
    float w0 = 1.0f / (1.0f + ew);
    float w1 = ew * w0;
    tok_e[t * 2 + 0] = i0; tok_w[t * 2 + 0] = w0;
    tok_e[t * 2 + 1] = i1; tok_w[t * 2 + 1] = w1;
  }
}

// ---------------- count / scan / scatter ----------------
__global__ __launch_bounds__(256) void count_kernel(const int* __restrict__ tok_e,
                                                    int* __restrict__ counts) {
  __shared__ int h[NEXP];
  int tid = threadIdx.x;
  if (tid < NEXP) h[tid] = 0;
  __syncthreads();
  int i = blockIdx.x * 256 + tid;
  atomicAdd(&h[tok_e[i]], 1);
  __syncthreads();
  if (tid < NEXP && h[tid] > 0) atomicAdd(&counts[tid], h[tid]);
}

__global__ void scan_kernel(const int* __restrict__ counts, int* __restrict__ base) {
  if (threadIdx.x == 0 && blockIdx.x == 0) {
    int s = 0;
    for (int e = 0; e < NEXP; ++e) { base[e] = s; s += counts[e]; }
  }
}

__global__ __launch_bounds__(256) void scatter_kernel(const int* __restrict__ tok_e,
                                                      const float* __restrict__ tok_w,
                                                      const int* __restrict__ base,
                                                      int* __restrict__ cursor,
                                                      int* __restrict__ pair_tok,
                                                      float* __restrict__ pair_w) {
  __shared__ int h[NEXP], bstart[NEXP];
  int tid = threadIdx.x;
  if (tid < NEXP) h[tid] = 0;
  __syncthreads();
  int i = blockIdx.x * 256 + tid;
  int e = tok_e[i];
  int r = atomicAdd(&h[e], 1);
  __syncthreads();
  if (tid < NEXP) bstart[tid] = (h[tid] > 0) ? atomicAdd(&cursor[tid], h[tid]) : 0;
  __syncthreads();
  int pos = base[e] + bstart[e] + r;
  pair_tok[pos] = i;          // packed (tok<<1)|slot
  pair_w[pos] = tok_w[i];
}

// ---------------- grouped GEMM, 256x256 tile, BK=64, 8 waves, 4-phase ----------------
// MODE 0: H = gelu(X * Wi^T + bi) -> hbuf (bf16), A gathered via pair_tok, K=768
// MODE 1: stage = (H * Wo^T + bo) * w      (f32), A contiguous (hbuf),    K=3072
template <int MODE>
__global__ __launch_bounds__(512, 2) void moe_gemm(
    const unsigned short* __restrict__ abase,
    const unsigned short* __restrict__ wbase,
    const float* __restrict__ bias,
    const int* __restrict__ counts, const int* __restrict__ base,
    const int* __restrict__ pair_tok, const float* __restrict__ pair_w,
    unsigned short* __restrict__ hbuf, float* __restrict__ stage) {
  constexpr int K  = MODE ? FDIM : HDIM;
  constexpr int N  = MODE ? HDIM : FDIM;
  constexpr int NT = K / 64;

  const int e = blockIdx.z;
  const int ne = counts[e];
  const int mt = blockIdx.y;
  if (mt * 256 >= ne) return;
  const int nt = blockIdx.x;
  const int pb = base[e];

  extern __shared__ char smem[];   // [2][ A 32KB | B 32KB ] = 128 KB

  const int tid = threadIdx.x;     // 0..511
  const int lane = tid & 63;
  const int wv = tid >> 6;         // 8 waves
  const int wm = wv >> 2;          // 0..1 (128 rows each)
  const int wn = wv & 3;           // 0..3 (64 cols each)
  const int l15 = lane & 15;
  const int lkb = (lane >> 4) * 16;  // byte offset of k-fragment

  // ---- staging source addresses (pre-swizzled global so LDS lands swizzled)
  const int crow = tid >> 3;       // row within a 64-row chunk
  const int ck = tid & 7;          // 16B column chunk
  const int swz = (ck ^ (crow & 7)) * 16;
  const char* aS[4]; const char* bS[4];
#pragma unroll
  for (int i = 0; i < 4; ++i) {
    int gr = mt * 256 + i * 64 + crow; if (gr > ne - 1) gr = ne - 1;
    if constexpr (MODE == 0) {
      int tok = pair_tok[pb + gr] >> 1;
      aS[i] = (const char*)abase + (size_t)tok * (HDIM * 2) + swz;
    } else {
      aS[i] = (const char*)abase + (size_t)(pb + gr) * (FDIM * 2) + swz;
    }
    int br = nt * 256 + i * 64 + crow;
    bS[i] = (const char*)wbase + ((size_t)e * N * K + (size_t)br * K) * 2 + swz;
  }

  auto STAGE = [&](int c, int t) {   // chunk c (0-3: A rows c*64.., 4-7: B), K-tile t
    if (t < NT) {
      const char* src = (c < 4 ? aS[c] : bS[c - 4]) + t * 128;
      char* dst = smem + (size_t)((t & 1) * 65536 + c * 8192 + tid * 16);
      __builtin_amdgcn_global_load_lds(
          (const __attribute__((address_space(1))) void*)src,
          (__attribute__((address_space(3))) void*)dst, 16, 0, 0);
    }
  };

  bf16x8 aR[8], bR0[4], bR1[4];
  f32x4 acc[8][4];
#pragma unroll
  for (int mi = 0; mi < 8; ++mi)
#pragma unroll
    for (int ni = 0; ni < 4; ++ni) acc[mi][ni] = (f32x4){0.f, 0.f, 0.f, 0.f};

  auto READA = [&](int cb, int h) {
#pragma unroll
    for (int m2 = 0; m2 < 4; ++m2)
#pragma unroll
      for (int k2 = 0; k2 < 2; ++k2) {
        int lr = wm * 128 + (h * 4 + m2) * 16 + l15;
        int cbyte = k2 * 64 + lkb;
        aR[m2 * 2 + k2] =
            *(const bf16x8*)(smem + cb + lr * 128 + (cbyte ^ ((lr & 7) << 4)));
      }
  };
  auto READB = [&](int cb, int h, bf16x8* bR) {
#pragma unroll
    for (int n2 = 0; n2 < 2; ++n2)
#pragma unroll
      for (int k2 = 0; k2 < 2; ++k2) {
        int lr = wn * 64 + (h * 2 + n2) * 16 + l15;
        int cbyte = k2 * 64 + lkb;
        bR[n2 * 2 + k2] =
            *(const bf16x8*)(smem + cb + 32768 + lr * 128 + (cbyte ^ ((lr & 7) << 4)));
      }
  };
  auto MFMAQ = [&](int qm, int qn, const bf16x8* bR) {
#pragma unroll
    for (int m2 = 0; m2 < 4; ++m2)
#pragma unroll
      for (int n2 = 0; n2 < 2; ++n2)
#pragma unroll
        for (int k2 = 0; k2 < 2; ++k2)
          acc[qm * 4 + m2][qn * 2 + n2] =
              mfma16(aR[m2 * 2 + k2], bR[n2 * 2 + k2], acc[qm * 4 + m2][qn * 2 + n2]);
  };

  // ---- prologue: tile0 fully, tile1 chunks 0,1 (10 loads in flight)
#pragma unroll
  for (int c = 0; c < 8; ++c) STAGE(c, 0);
  STAGE(0, 1); STAGE(1, 1);
  asm volatile("s_waitcnt vmcnt(2)" ::: "memory");
  __builtin_amdgcn_s_barrier();

  for (int t = 0; t < NT; ++t) {
    const int cb = (t & 1) * 65536;
    // phase 0: read A-half0 + B-half0; stage chunks 2,3 of t+1
    READA(cb, 0); READB(cb, 0, bR0);
    STAGE(2, t + 1); STAGE(3, t + 1);
    __builtin_amdgcn_s_barrier();
    asm volatile("s_waitcnt lgkmcnt(0)" ::: "memory");
    __builtin_amdgcn_sched_barrier(0);
    __builtin_amdgcn_s_setprio(1);
    MFMAQ(0, 0, bR0);
    __builtin_amdgcn_s_setprio(0);
    __builtin_amdgcn_s_barrier();
    // phase 1: read B-half1; stage 4,5 of t+1
    READB(cb, 1, bR1);
    STAGE(4, t + 1); STAGE(5, t + 1);
    __builtin_amdgcn_s_barrier();
    asm volatile("s_waitcnt lgkmcnt(0)" ::: "memory");
    __builtin_amdgcn_sched_barrier(0);
    __builtin_amdgcn_s_setprio(1);
    MFMAQ(0, 1, bR1);
    __builtin_amdgcn_s_setprio(0);
    __builtin_amdgcn_s_barrier();
    // phase 2: read A-half1; stage 6,7 of t+1
    READA(cb, 1);
    STAGE(6, t + 1); STAGE(7, t + 1);
    __builtin_amdgcn_s_barrier();
    asm volatile("s_waitcnt lgkmcnt(0)" ::: "memory");
    __builtin_amdgcn_sched_barrier(0);
    __builtin_amdgcn_s_setprio(1);
    MFMAQ(1, 1, bR1);
    __builtin_amdgcn_s_setprio(0);
    __builtin_amdgcn_s_barrier();
    // phase 3: stage chunks 0,1 of t+2 into cur (reads of cur finished at phase 2)
    STAGE(0, t + 2); STAGE(1, t + 2);
    __builtin_amdgcn_s_barrier();
    __builtin_amdgcn_s_setprio(1);
    MFMAQ(1, 0, bR0);
    __builtin_amdgcn_s_setprio(0);
    if (t + 2 < NT) asm volatile("s_waitcnt vmcnt(2)" ::: "memory");
    else            asm volatile("s_waitcnt vmcnt(0)" ::: "memory");
    __builtin_amdgcn_s_barrier();
  }

  // ---- epilogue
  if constexpr (MODE == 0) {
    const float* be = bias + (size_t)e * FDIM;
    float bv[4];
#pragma unroll
    for (int ni = 0; ni < 4; ++ni) bv[ni] = be[nt * 256 + wn * 64 + ni * 16 + l15];
#pragma unroll
    for (int mi = 0; mi < 8; ++mi)
#pragma unroll
      for (int r = 0; r < 4; ++r) {
        int row = mt * 256 + wm * 128 + mi * 16 + (lane >> 4) * 4 + r;
        if (row < ne) {
          unsigned short* hr = hbuf + (size_t)(pb + row) * FDIM + nt * 256 + wn * 64 + l15;
#pragma unroll
          for (int ni = 0; ni < 4; ++ni) {
            float v = acc[mi][ni][r] + bv[ni];
            v = 0.5f * v * (1.0f + erff(v * 0.70710678118654752f));
            hr[ni * 16] = f2b(v);
          }
        }
      }
  } else {
    const float* be = bias + (size_t)e * HDIM;
    float bv[4];
#pragma unroll
    for (int ni = 0; ni < 4; ++ni) bv[ni] = be[nt * 256 + wn * 64 + ni * 16 + l15];
#pragma unroll
    for (int mi = 0; mi < 8; ++mi)
#pragma unroll
      for (int r = 0; r < 4; ++r) {
        int row = mt * 256 + wm * 128 + mi * 16 + (lane >> 4) * 4 + r;
        if (row < ne) {
          int p = pb + row;
          int ts = pair_tok[p];        // (tok<<1)|slot in [0,16384)
          float w = pair_w[p];
          float* sr = stage + (size_t)ts * HDIM + nt * 256 + wn * 64 + l15;
#pragma unroll
          for (int ni = 0; ni < 4; ++ni)
            sr[ni * 16] = (acc[mi][ni][r] + bv[ni]) * w;
        }
      }
  }
}

// ---------------- combine: out[t] = stage[2t] + stage[2t+1] ----------------
__global__ __launch_bounds__(256) void combine_kernel(const float* __restrict__ stage,
                                                      float* __restrict__ out) {
  const int n4 = T_TOK * HDIM / 4;               // 1,572,864 float4
  int i = blockIdx.x * 256 + threadIdx.x;
  int stride = gridDim.x * 256;
  const float4* s = (const float4*)stage;
  float4* o = (float4*)out;
  for (; i < n4; i += stride) {
    int t = i / (HDIM / 4);
    int h = i - t * (HDIM / 4);
    float4 a = s[(size_t)t * (HDIM / 2) + h];
    float4 b = s[(size_t)t * (HDIM / 2) + (HDIM / 4) + h];
    float4 r; r.x = a.x + b.x; r.y = a.y + b.y; r.z = a.z + b.z; r.w = a.w + b.w;
    o[i] = r;
  }
}

extern "C" void kernel_launch(void* const* d_in, const int* in_sizes, int n_in,
                              void* d_out, int out_size, void* d_ws, size_t ws_size,
                              hipStream_t stream) {
  const float* x  = (const float*)d_in[0];
  const float* Wr = (const float*)d_in[1];
  const float* Wi = (const float*)d_in[2];
  const float* bi = (const float*)d_in[3];
  const float* Wo = (const float*)d_in[4];
  const float* bo = (const float*)d_in[5];
  float* out = (float*)d_out;
  char* ws = (char*)d_ws;

  unsigned short* xb   = (unsigned short*)(ws + OFF_XB);
  unsigned short* wib  = (unsigned short*)(ws + OFF_WIB);
  unsigned short* wob  = (unsigned short*)(ws + OFF_WOB);
  unsigned short* hbuf = (unsigned short*)(ws + OFF_HBUF);
  int*   counts   = (int*)(ws + OFF_META);
  int*   basep    = (int*)(ws + OFF_META + 64);
  int*   cursor   = (int*)(ws + OFF_META + 128);
  int*   tok_e    = (int*)(ws + OFF_TOKE);
  float* tok_w    = (float*)(ws + OFF_TOKW);
  int*   pair_tok = (int*)(ws + OFF_PTOK);
  float* pair_w   = (float*)(ws + OFF_PW);
  float* stage    = (float*)(ws + OFF_STAGE);   // aliases xb+wib (dead after gemmA)

  hipFuncSetAttribute((const void*)&moe_gemm<0>,
                      hipFuncAttributeMaxDynamicSharedMemorySize, 131072);
  hipFuncSetAttribute((const void*)&moe_gemm<1>,
                      hipFuncAttributeMaxDynamicSharedMemorySize, 131072);

  hipMemsetAsync(ws + OFF_META, 0, 256, stream);

  cvt_kernel<<<1024, 256, 0, stream>>>(x, xb, T_TOK * HDIM / 4);
  cvt_kernel<<<2048, 256, 0, stream>>>(Wi, wib, NEXP * FDIM * HDIM / 4);
  cvt_kernel<<<2048, 256, 0, stream>>>(Wo, wob, NEXP * HDIM * FDIM / 4);

  router_kernel<<<T_TOK / 4, 256, 0, stream>>>(x, Wr, tok_e, tok_w);
  count_kernel<<<64, 256, 0, stream>>>(tok_e, counts);
  scan_kernel<<<1, 64, 0, stream>>>(counts, basep);
  scatter_kernel<<<64, 256, 0, stream>>>(tok_e, tok_w, basep, cursor, pair_tok, pair_w);

  moe_gemm<0><<<dim3(FDIM / 256, T_TOK / 256, NEXP), 512, 131072, stream>>>(
      xb, wib, bi, counts, basep, pair_tok, pair_w, hbuf, nullptr);
  moe_gemm<1><<<dim3(HDIM / 256, T_TOK / 256, NEXP), 512, 131072, stream>>>(
      hbuf, wob, bo, counts, basep, pair_tok, pair_w, nullptr, stage);

  combine_kernel<<<2048, 256, 0, stream>>>(stage, out);
}